// Round 11
// baseline (344.042 us; speedup 1.0000x reference)
//
#include <hip/hip_runtime.h>
#include <hip/hip_bf16.h>

#define BATCH 32768
#define TSEQ 200

typedef __attribute__((ext_vector_type(8))) short short8;
typedef __attribute__((ext_vector_type(4))) float floatx4;
typedef __attribute__((ext_vector_type(2))) __fp16 h16x2;

#if __has_builtin(__builtin_amdgcn_exp2f)
__device__ __forceinline__ float EXP2(float x) { return __builtin_amdgcn_exp2f(x); }
#else
__device__ __forceinline__ float EXP2(float x) {
    float r; asm("v_exp_f32 %0, %1" : "=v"(r) : "v"(x)); return r;
}
#endif
__device__ __forceinline__ float RCP(float x) { return __builtin_amdgcn_rcpf(x); }

__device__ __forceinline__ float fast_sigmoid(float x) {
    return RCP(1.0f + EXP2(-1.4426950408889634f * x));
}
__device__ __forceinline__ float fast_tanh(float x) {
    float e = EXP2(2.8853900817779268f * x);
    return 1.0f - 2.0f * RCP(e + 1.0f);
}
__device__ __forceinline__ short f2bfs(float v) {
    __hip_bfloat16 h = __float2bfloat16(v);
    return __builtin_bit_cast(short, h);
}
__device__ __forceinline__ h16x2 pkh(float a, float b) {
    return __builtin_amdgcn_cvt_pkrtz(a, b);
}
__device__ __forceinline__ float DOT2(h16x2 a, h16x2 b, float c) {
    return __builtin_amdgcn_fdot2(a, b, c, false);
}
template <int K>
__device__ __forceinline__ int qbi(int i) {
    return __builtin_amdgcn_update_dpp(i, i, K * 0x55, 0xf, 0xf, false);
}
template <int K>
__device__ __forceinline__ float qbf(float v) {
    return __builtin_bit_cast(float, qbi<K>(__builtin_bit_cast(int, v)));
}
template <int K>
__device__ __forceinline__ h16x2 qbh(h16x2 v) {
    return __builtin_bit_cast(h16x2, qbi<K>(__builtin_bit_cast(int, v)));
}
__device__ __forceinline__ void async16(void* lds, const void* g) {
    __builtin_amdgcn_global_load_lds(
        (const __attribute__((address_space(1))) unsigned int*)g,
        (__attribute__((address_space(3))) unsigned int*)lds, 16, 0, 0);
}

#define S_SIG (-1.4426950408889634f)   // sigmoid rows: 2^(S_SIG*g) = e^-g
#define S_TANH (2.8853900817779268f)   // tanh rows:    2^(S_TANH*g) = e^(2g)

// ---------------- workspace layout (bytes) ----------------
// hh k-index: k' = (t>>2)*16 + q*4 + (t&3)  — quad-contiguous 32B stores
#define WS_HH  0                         // bf16 [2][B][800]
#define WS_WHB 104857600                 // bf16 [128][800] cols permuted to k'
#define WS_WLB (WS_WHB + 204800)
#define WS_W1B (WS_WLB + 204800)         // bf16 [80][256]
#define WS_W2B (WS_W1B + 40960)          // bf16 [48][96] zero-pad
#define WS_U   (WS_W2B + 9216)           // f32 [401]
#define WS_OT  (WS_U + 1616)             // f32 [2][B]
#define WS_Z   (WS_OT + 262144)          // bf16 [B][256]

struct LW { const float* p[16]; };

// ---------------- kernel 0: weight prep / folds ----------------
__global__ __launch_bounds__(256) void k_prep(
    const float* __restrict__ WH, const float* __restrict__ WL,
    const float* __restrict__ W1, const float* __restrict__ W2,
    const float* __restrict__ W3, const float* __restrict__ Wp,
    const float* __restrict__ bp, const float* __restrict__ b3,
    __hip_bfloat16* __restrict__ WHbf, __hip_bfloat16* __restrict__ WLbf,
    __hip_bfloat16* __restrict__ W1bf, __hip_bfloat16* __restrict__ W2bf,
    float* __restrict__ u)
{
    int gid = blockIdx.x * 256 + threadIdx.x;   // 400 blocks = 102400 = 128*800
    int n = gid / 800, k = gid - n * 800;
    int t = k >> 2, q = k & 3;
    int kp = (t >> 2) * 16 + q * 4 + (t & 3);
    int dst = n * 800 + kp;
    WHbf[dst] = __float2bfloat16(WH[gid]);
    WLbf[dst] = __float2bfloat16(WL[gid]);
    if (gid < 20480) W1bf[gid] = __float2bfloat16(W1[gid]);
    if (gid < 4608) {
        int rr = gid / 96, cc = gid - rr * 96;
        float v = (rr < 40 && cc < 80) ? W2[rr * 80 + cc] : 0.0f;
        W2bf[gid] = __float2bfloat16(v);
    }
    if (gid < 400) {
        float a = 0.f;
        for (int j = 0; j < 40; ++j) a = fmaf(W3[40 + j], Wp[j * 400 + gid], a);
        u[gid] = a;
    } else if (gid == 400) {
        float a = b3[0];
        for (int j = 0; j < 40; ++j) a = fmaf(W3[40 + j], bp[j], a);
        u[400] = a;
    }
}

// one LSTM step for both layers; everything scalar, no arrays
#define LSTM_STEP(XT, HOUT)                                                   \
    do {                                                                      \
        float a0 = qbf<0>(h0), a1 = qbf<1>(h0), a2 = qbf<2>(h0),              \
              a3 = qbf<3>(h0);                                                \
        h16x2 a01 = pkh(a0, a1), a23 = pkh(a2, a3);                           \
        float gi = DOT2(w0a[0], a01, DOT2(w0b[0], a23, fmaf(XT, wx0[0], bb0[0]))); \
        float gf = DOT2(w0a[1], a01, DOT2(w0b[1], a23, fmaf(XT, wx0[1], bb0[1]))); \
        float gg = DOT2(w0a[2], a01, DOT2(w0b[2], a23, fmaf(XT, wx0[2], bb0[2]))); \
        float go = DOT2(w0a[3], a01, DOT2(w0b[3], a23, fmaf(XT, wx0[3], bb0[3]))); \
        float ig = RCP(1.0f + EXP2(gi));                                      \
        float fg = RCP(1.0f + EXP2(gf));                                      \
        float tg = 1.0f - 2.0f * RCP(EXP2(gg) + 1.0f);                        \
        float og = RCP(1.0f + EXP2(go));                                      \
        c0 = fmaf(fg, c0, ig * tg);                                           \
        h0 = og * (1.0f - 2.0f * RCP(EXP2(S_TANH * c0) + 1.0f));              \
        h16x2 hhpk = pkh(h0, h1);                                             \
        h16x2 e0 = qbh<0>(hhpk), e1 = qbh<1>(hhpk);                           \
        h16x2 e2 = qbh<2>(hhpk), e3 = qbh<3>(hhpk);                           \
        gi = DOT2(w1h[0][0], e0, DOT2(w1h[0][1], e1,                          \
             DOT2(w1h[0][2], e2, DOT2(w1h[0][3], e3, bb1[0]))));              \
        gf = DOT2(w1h[1][0], e0, DOT2(w1h[1][1], e1,                          \
             DOT2(w1h[1][2], e2, DOT2(w1h[1][3], e3, bb1[1]))));              \
        gg = DOT2(w1h[2][0], e0, DOT2(w1h[2][1], e1,                          \
             DOT2(w1h[2][2], e2, DOT2(w1h[2][3], e3, bb1[2]))));              \
        go = DOT2(w1h[3][0], e0, DOT2(w1h[3][1], e1,                          \
             DOT2(w1h[3][2], e2, DOT2(w1h[3][3], e3, bb1[3]))));              \
        ig = RCP(1.0f + EXP2(gi));                                            \
        fg = RCP(1.0f + EXP2(gf));                                            \
        tg = 1.0f - 2.0f * RCP(EXP2(gg) + 1.0f);                              \
        og = RCP(1.0f + EXP2(go));                                            \
        c1 = fmaf(fg, c1, ig * tg);                                           \
        h1 = og * (1.0f - 2.0f * RCP(EXP2(S_TANH * c1) + 1.0f));              \
        HOUT = h1;                                                            \
    } while (0)

// ---------------- kernel 1: fused 2-layer LSTM (both rnns) ----------------
// 4 lanes per (b,r); f16 dot2 weights; fully scalarized inner loop (no local
// arrays -> nothing for the allocator to demote to scratch), prefetched x/u.
__global__ __launch_bounds__(256)
__attribute__((amdgpu_waves_per_eu(4, 4))) void k_lstm(
    const float* __restrict__ x, LW w, const float* __restrict__ u,
    __hip_bfloat16* __restrict__ hh, float* __restrict__ otherp)
{
    int gid = blockIdx.x * 256 + threadIdx.x;
    int q = gid & 3;
    int group = gid >> 2;
    int b = group & (BATCH - 1);
    int r = group >> 15;                 // wave-uniform

    const float* Wih0 = w.p[r * 8 + 0];
    const float* Whh0 = w.p[r * 8 + 1];
    const float* bih0 = w.p[r * 8 + 2];
    const float* bhh0 = w.p[r * 8 + 3];
    const float* Wih1 = w.p[r * 8 + 4];
    const float* Whh1 = w.p[r * 8 + 5];
    const float* bih1 = w.p[r * 8 + 6];
    const float* bhh1 = w.p[r * 8 + 7];

    // G: 0=i, 1=f, 2=g(tanh), 3=o ; row j = 4*G + q
    float wx0[4], bb0[4], bb1[4];
    h16x2 w0a[4], w0b[4];     // layer0 Whh pairs (k01), (k23)
    h16x2 w1h[4][4];          // layer1 (Wih[k], Whh[k]) pairs
#pragma unroll
    for (int G = 0; G < 4; ++G) {
        int j = 4 * G + q;
        float sc = (G == 2) ? S_TANH : S_SIG;
        wx0[G] = Wih0[j] * sc;
        bb0[G] = (bih0[j] + bhh0[j]) * sc;
        bb1[G] = (bih1[j] + bhh1[j]) * sc;
        w0a[G] = pkh(Whh0[j * 4 + 0] * sc, Whh0[j * 4 + 1] * sc);
        w0b[G] = pkh(Whh0[j * 4 + 2] * sc, Whh0[j * 4 + 3] * sc);
#pragma unroll
        for (int k = 0; k < 4; ++k)
            w1h[G][k] = pkh(Wih1[j * 4 + k] * sc, Whh1[j * 4 + k] * sc);
    }

    const float* xp = x + ((size_t)b * 2 + r) * TSEQ;
    const float* up = u + r * TSEQ;
    __hip_bfloat16* hp = hh + ((size_t)r * BATCH + b) * 800 + q * 4;

    float h0 = 0.f, c0 = 0.f, h1 = 0.f, c1 = 0.f, accO = 0.f;

    float4 xv = *(const float4*)xp;
    float4 uv = *(const float4*)up;

    for (int tb = 0; tb < TSEQ; tb += 4) {
        // consume current, prefetch next block before the serial chain
        float x0 = xv.x, x1 = xv.y, x2 = xv.z, x3 = xv.w;
        float u0 = uv.x, u1 = uv.y, u2 = uv.z, u3 = uv.w;
        if (tb + 4 < TSEQ) {
            xv = *(const float4*)(xp + tb + 4);
            uv = *(const float4*)(up + tb + 4);
        }
        accO = fmaf(x0, u0, accO);
        accO = fmaf(x1, u1, accO);
        accO = fmaf(x2, u2, accO);
        accO = fmaf(x3, u3, accO);

        float o0, o1, o2, o3;
        LSTM_STEP(x0, o0);
        LSTM_STEP(x1, o1);
        LSTM_STEP(x2, o2);
        LSTM_STEP(x3, o3);

        ushort4 pk;
        pk.x = (unsigned short)f2bfs(o0);
        pk.y = (unsigned short)f2bfs(o1);
        pk.z = (unsigned short)f2bfs(o2);
        pk.w = (unsigned short)f2bfs(o3);
        *(ushort4*)(hp + tb * 4) = pk;   // k' = tb*4 + q*4 + 0..3; quad = 32B contig
    }
    if (q == 0) otherp[(size_t)r * BATCH + b] = accO;
}

// ---------------- kernel 2: pipelined bf16 GEMM  z = tanh(hh @ W.T + b) ----------------
// grid (256, 2): 128 rows x 128 cols, K=800 in chunks of 32, LDS double-buffered.
__global__ __launch_bounds__(256) void k_gemm(
    const __hip_bfloat16* __restrict__ hh,
    const __hip_bfloat16* __restrict__ WHbf, const __hip_bfloat16* __restrict__ WLbf,
    const float* __restrict__ bH, const float* __restrict__ bL,
    __hip_bfloat16* __restrict__ zws)
{
    __shared__ __hip_bfloat16 As[2][128 * 32];
    __shared__ __hip_bfloat16 Bs[2][128 * 32];
    int tid = threadIdx.x;
    int f = blockIdx.y;
    int m0 = blockIdx.x * 128;
    const __hip_bfloat16* A = hh + (size_t)f * BATCH * 800 + (size_t)m0 * 800;
    const __hip_bfloat16* Wb = f ? WLbf : WHbf;
    const float* bias = f ? bL : bH;

    int wv = tid >> 6, lane = tid & 63, l15 = lane & 15, quad = lane >> 4;
    const __hip_bfloat16* ga = A + (size_t)(tid >> 2) * 800 + (tid & 3) * 8;
    const __hip_bfloat16* gb = Wb + (size_t)(tid >> 2) * 800 + (tid & 3) * 8;

    floatx4 acc[2][8] = {};

#define PREFETCH(kc, buf)                                              \
    do {                                                               \
        __hip_bfloat16* la = &As[buf][wv * 512];                       \
        __hip_bfloat16* lb = &Bs[buf][wv * 512];                       \
        async16(la,        ga + (kc) * 32);                            \
        async16(lb,        gb + (kc) * 32);                            \
        async16(la + 2048, ga + 64 * 800 + (kc) * 32);                 \
        async16(lb + 2048, gb + 64 * 800 + (kc) * 32);                 \
    } while (0)

    PREFETCH(0, 0);
    for (int kc = 0; kc < 25; ++kc) {
        __syncthreads();
        if (kc < 24) PREFETCH(kc + 1, (kc + 1) & 1);
        int buf = kc & 1;
        short8 af0 = *(const short8*)(const void*)&As[buf][(wv * 32 + l15) * 32 + quad * 8];
        short8 af1 = *(const short8*)(const void*)&As[buf][(wv * 32 + 16 + l15) * 32 + quad * 8];
#pragma unroll
        for (int nt = 0; nt < 8; ++nt) {
            short8 bfr = *(const short8*)(const void*)&Bs[buf][(nt * 16 + l15) * 32 + quad * 8];
            acc[0][nt] = __builtin_amdgcn_mfma_f32_16x16x32_bf16(af0, bfr, acc[0][nt], 0, 0, 0);
            acc[1][nt] = __builtin_amdgcn_mfma_f32_16x16x32_bf16(af1, bfr, acc[1][nt], 0, 0, 0);
        }
    }
#undef PREFETCH

    float bv[8];
#pragma unroll
    for (int nt = 0; nt < 8; ++nt) bv[nt] = bias[nt * 16 + l15];
#pragma unroll
    for (int mt = 0; mt < 2; ++mt)
#pragma unroll
        for (int nt = 0; nt < 8; ++nt)
#pragma unroll
            for (int rg = 0; rg < 4; ++rg) {
                int row = m0 + wv * 32 + mt * 16 + quad * 4 + rg;
                int col = f * 128 + nt * 16 + l15;
                zws[(size_t)row * 256 + col] =
                    __float2bfloat16(fast_tanh(acc[mt][nt][rg] + bv[nt]));
            }
}

// ---------------- kernel 3: MLP tail on z ----------------
__global__ __launch_bounds__(256) void k_tail(
    const __hip_bfloat16* __restrict__ zws,
    const __hip_bfloat16* __restrict__ W1bf, const __hip_bfloat16* __restrict__ W2bf,
    const float* __restrict__ b1, const float* __restrict__ b2,
    const float* __restrict__ W3, const float* __restrict__ u,
    const float* __restrict__ otherp, float* __restrict__ out)
{
    __shared__ short z1sh[64 * 104];
    __shared__ float z2sh[64 * 49];
    int tid = threadIdx.x;
    int wv = tid >> 6, lane = tid & 63, l15 = lane & 15, quad = lane >> 4;
    int m0 = blockIdx.x * 64;

    for (int i = tid; i < 64 * 24; i += 256) {
        int rr = i / 24, cc = 80 + (i - rr * 24);
        z1sh[rr * 104 + cc] = 0;
    }

    // z1 = tanh(z @ W1.T + b1)   M=64 K=256 N=80
    {
        floatx4 acc[5] = {};
#pragma unroll
        for (int kc = 0; kc < 8; ++kc) {
            short8 af = *(const short8*)(const void*)
                (zws + (size_t)(m0 + wv * 16 + l15) * 256 + kc * 32 + quad * 8);
#pragma unroll
            for (int nt = 0; nt < 5; ++nt) {
                short8 bfr = *(const short8*)(const void*)
                    (W1bf + (size_t)(nt * 16 + l15) * 256 + kc * 32 + quad * 8);
                acc[nt] = __builtin_amdgcn_mfma_f32_16x16x32_bf16(af, bfr, acc[nt], 0, 0, 0);
            }
        }
#pragma unroll
        for (int nt = 0; nt < 5; ++nt) {
            int n = nt * 16 + l15;
            float bb = b1[n];
#pragma unroll
            for (int rg = 0; rg < 4; ++rg) {
                int ml = wv * 16 + quad * 4 + rg;
                z1sh[ml * 104 + n] = f2bfs(fast_tanh(acc[nt][rg] + bb));
            }
        }
    }
    __syncthreads();

    // z2 = tanh(z1 @ W2.T + b2)  M=64 K=96(pad) N=48(keep 40)
    {
        floatx4 acc[3] = {};
#pragma unroll
        for (int kc = 0; kc < 3; ++kc) {
            short8 af = *(const short8*)(const void*)
                &z1sh[(wv * 16 + l15) * 104 + kc * 32 + quad * 8];
#pragma unroll
            for (int nt = 0; nt < 3; ++nt) {
                short8 bfr = *(const short8*)(const void*)
                    (W2bf + (size_t)(nt * 16 + l15) * 96 + kc * 32 + quad * 8);
                acc[nt] = __builtin_amdgcn_mfma_f32_16x16x32_bf16(af, bfr, acc[nt], 0, 0, 0);
            }
        }
#pragma unroll
        for (int nt = 0; nt < 3; ++nt) {
            int n = nt * 16 + l15;
            if (n < 40) {
                float bb = b2[n];
#pragma unroll
                for (int rg = 0; rg < 4; ++rg) {
                    int ml = wv * 16 + quad * 4 + rg;
                    z2sh[ml * 49 + n] = fast_tanh(acc[nt][rg] + bb);
                }
            }
        }
    }
    __syncthreads();

    if (tid < 64) {
        int grow = m0 + tid;
        float s = u[400] + otherp[grow] + otherp[BATCH + grow];
        for (int j = 0; j < 40; ++j) s = fmaf(z2sh[tid * 49 + j], W3[j], s);
        out[grow] = fast_sigmoid(s);
    }
}

extern "C" void kernel_launch(void* const* d_in, const int* in_sizes, int n_in,
                              void* d_out, int out_size, void* d_ws, size_t ws_size,
                              hipStream_t stream)
{
    const float* x = (const float*)d_in[0];
    LW w;
    for (int i = 0; i < 16; ++i) w.p[i] = (const float*)d_in[1 + i];
    const float* Wp = (const float*)d_in[17];
    const float* bp = (const float*)d_in[18];
    const float* WH = (const float*)d_in[19];
    const float* bH = (const float*)d_in[20];
    const float* WL = (const float*)d_in[21];
    const float* bL = (const float*)d_in[22];
    const float* W1 = (const float*)d_in[23];
    const float* b1 = (const float*)d_in[24];
    const float* W2 = (const float*)d_in[25];
    const float* b2 = (const float*)d_in[26];
    const float* W3 = (const float*)d_in[27];
    const float* b3 = (const float*)d_in[28];

    char* ws = (char*)d_ws;
    __hip_bfloat16* hh   = (__hip_bfloat16*)(ws + WS_HH);
    __hip_bfloat16* WHbf = (__hip_bfloat16*)(ws + WS_WHB);
    __hip_bfloat16* WLbf = (__hip_bfloat16*)(ws + WS_WLB);
    __hip_bfloat16* W1bf = (__hip_bfloat16*)(ws + WS_W1B);
    __hip_bfloat16* W2bf = (__hip_bfloat16*)(ws + WS_W2B);
    float* u      = (float*)(ws + WS_U);
    float* otherp = (float*)(ws + WS_OT);
    __hip_bfloat16* zws = (__hip_bfloat16*)(ws + WS_Z);
    float* out = (float*)d_out;

    k_prep<<<400, 256, 0, stream>>>(WH, WL, W1, W2, W3, Wp, bp, b3,
                                    WHbf, WLbf, W1bf, W2bf, u);
    k_lstm<<<1024, 256, 0, stream>>>(x, w, u, hh, otherp);
    k_gemm<<<dim3(256, 2), 256, 0, stream>>>(hh, WHbf, WLbf, bH, bL, zws);
    k_tail<<<512, 256, 0, stream>>>(zws, W1bf, W2bf, b1, b2, W3, u, otherp, out);
}

// Round 12
// 341.681 us; speedup vs baseline: 1.0069x; 1.0069x over previous
//
#include <hip/hip_runtime.h>
#include <hip/hip_bf16.h>

#define BATCH 32768
#define TSEQ 200

typedef __attribute__((ext_vector_type(8))) short short8;
typedef __attribute__((ext_vector_type(4))) float floatx4;
typedef __attribute__((ext_vector_type(2))) __fp16 h16x2;

#if __has_builtin(__builtin_amdgcn_exp2f)
__device__ __forceinline__ float EXP2(float x) { return __builtin_amdgcn_exp2f(x); }
#else
__device__ __forceinline__ float EXP2(float x) {
    float r; asm("v_exp_f32 %0, %1" : "=v"(r) : "v"(x)); return r;
}
#endif
__device__ __forceinline__ float RCP(float x) { return __builtin_amdgcn_rcpf(x); }

__device__ __forceinline__ float fast_sigmoid(float x) {
    return RCP(1.0f + EXP2(-1.4426950408889634f * x));
}
__device__ __forceinline__ float fast_tanh(float x) {
    float e = EXP2(2.8853900817779268f * x);
    return 1.0f - 2.0f * RCP(e + 1.0f);
}
__device__ __forceinline__ short f2bfs(float v) {
    __hip_bfloat16 h = __float2bfloat16(v);
    return __builtin_bit_cast(short, h);
}
__device__ __forceinline__ h16x2 pkh(float a, float b) {
    return __builtin_amdgcn_cvt_pkrtz(a, b);
}
__device__ __forceinline__ float DOT2(h16x2 a, h16x2 b, float c) {
    return __builtin_amdgcn_fdot2(a, b, c, false);
}
template <int K>
__device__ __forceinline__ int qbi(int i) {
    return __builtin_amdgcn_update_dpp(i, i, K * 0x55, 0xf, 0xf, false);
}
template <int K>
__device__ __forceinline__ float qbf(float v) {
    return __builtin_bit_cast(float, qbi<K>(__builtin_bit_cast(int, v)));
}
template <int K>
__device__ __forceinline__ h16x2 qbh(h16x2 v) {
    return __builtin_bit_cast(h16x2, qbi<K>(__builtin_bit_cast(int, v)));
}
__device__ __forceinline__ void async16(void* lds, const void* g) {
    __builtin_amdgcn_global_load_lds(
        (const __attribute__((address_space(1))) unsigned int*)g,
        (__attribute__((address_space(3))) unsigned int*)lds, 16, 0, 0);
}

#define S_SIG (-1.4426950408889634f)
#define S_TANH (2.8853900817779268f)

// ---------------- workspace layout (bytes) ----------------
// hh k-index: k' = (t>>2)*16 + q*4 + (t&3)  — quad-contiguous 32B stores
#define WS_HH  0                         // bf16 [2][B][800]
#define WS_WHB 104857600                 // bf16 [128][800] cols permuted to k'
#define WS_WLB (WS_WHB + 204800)
#define WS_W1B (WS_WLB + 204800)         // bf16 [80][256]
#define WS_W2B (WS_W1B + 40960)          // bf16 [48][96] zero-pad
#define WS_U   (WS_W2B + 9216)           // f32 [401]
#define WS_OT  (WS_U + 1616)             // f32 [2][B]
#define WS_Z   (WS_OT + 262144)          // bf16 [B][256]

struct LW { const float* p[16]; };

// ---------------- kernel 0: weight prep / folds ----------------
__global__ __launch_bounds__(256) void k_prep(
    const float* __restrict__ WH, const float* __restrict__ WL,
    const float* __restrict__ W1, const float* __restrict__ W2,
    const float* __restrict__ W3, const float* __restrict__ Wp,
    const float* __restrict__ bp, const float* __restrict__ b3,
    __hip_bfloat16* __restrict__ WHbf, __hip_bfloat16* __restrict__ WLbf,
    __hip_bfloat16* __restrict__ W1bf, __hip_bfloat16* __restrict__ W2bf,
    float* __restrict__ u)
{
    int gid = blockIdx.x * 256 + threadIdx.x;   // 400 blocks = 102400 = 128*800
    int n = gid / 800, k = gid - n * 800;
    int t = k >> 2, q = k & 3;
    int kp = (t >> 2) * 16 + q * 4 + (t & 3);
    int dst = n * 800 + kp;
    WHbf[dst] = __float2bfloat16(WH[gid]);
    WLbf[dst] = __float2bfloat16(WL[gid]);
    if (gid < 20480) W1bf[gid] = __float2bfloat16(W1[gid]);
    if (gid < 4608) {
        int rr = gid / 96, cc = gid - rr * 96;
        float v = (rr < 40 && cc < 80) ? W2[rr * 80 + cc] : 0.0f;
        W2bf[gid] = __float2bfloat16(v);
    }
    if (gid < 400) {
        float a = 0.f;
        for (int j = 0; j < 40; ++j) a = fmaf(W3[40 + j], Wp[j * 400 + gid], a);
        u[gid] = a;
    } else if (gid == 400) {
        float a = b3[0];
        for (int j = 0; j < 40; ++j) a = fmaf(W3[40 + j], bp[j], a);
        u[400] = a;
    }
}

// one 2-layer LSTM step for chain S (state h0S,c0S,h1S,c1S)
#define LSTM_STEP(S, XT, HOUT)                                                \
    do {                                                                      \
        float a0 = qbf<0>(h0##S), a1 = qbf<1>(h0##S), a2 = qbf<2>(h0##S),     \
              a3 = qbf<3>(h0##S);                                             \
        h16x2 a01 = pkh(a0, a1), a23 = pkh(a2, a3);                           \
        float gi = DOT2(w0a[0], a01, DOT2(w0b[0], a23, fmaf(XT, wx0[0], bb0[0]))); \
        float gf = DOT2(w0a[1], a01, DOT2(w0b[1], a23, fmaf(XT, wx0[1], bb0[1]))); \
        float gg = DOT2(w0a[2], a01, DOT2(w0b[2], a23, fmaf(XT, wx0[2], bb0[2]))); \
        float go = DOT2(w0a[3], a01, DOT2(w0b[3], a23, fmaf(XT, wx0[3], bb0[3]))); \
        float ig = RCP(1.0f + EXP2(gi));                                      \
        float fg = RCP(1.0f + EXP2(gf));                                      \
        float tg = 1.0f - 2.0f * RCP(EXP2(gg) + 1.0f);                        \
        float og = RCP(1.0f + EXP2(go));                                      \
        c0##S = fmaf(fg, c0##S, ig * tg);                                     \
        h0##S = og * (1.0f - 2.0f * RCP(EXP2(S_TANH * c0##S) + 1.0f));        \
        h16x2 hhpk = pkh(h0##S, h1##S);                                       \
        h16x2 e0 = qbh<0>(hhpk), e1 = qbh<1>(hhpk);                           \
        h16x2 e2 = qbh<2>(hhpk), e3 = qbh<3>(hhpk);                           \
        gi = DOT2(w1h[0][0], e0, DOT2(w1h[0][1], e1,                          \
             DOT2(w1h[0][2], e2, DOT2(w1h[0][3], e3, bb1[0]))));              \
        gf = DOT2(w1h[1][0], e0, DOT2(w1h[1][1], e1,                          \
             DOT2(w1h[1][2], e2, DOT2(w1h[1][3], e3, bb1[1]))));              \
        gg = DOT2(w1h[2][0], e0, DOT2(w1h[2][1], e1,                          \
             DOT2(w1h[2][2], e2, DOT2(w1h[2][3], e3, bb1[2]))));              \
        go = DOT2(w1h[3][0], e0, DOT2(w1h[3][1], e1,                          \
             DOT2(w1h[3][2], e2, DOT2(w1h[3][3], e3, bb1[3]))));              \
        ig = RCP(1.0f + EXP2(gi));                                            \
        fg = RCP(1.0f + EXP2(gf));                                            \
        tg = 1.0f - 2.0f * RCP(EXP2(gg) + 1.0f);                              \
        og = RCP(1.0f + EXP2(go));                                            \
        c1##S = fmaf(fg, c1##S, ig * tg);                                     \
        h1##S = og * (1.0f - 2.0f * RCP(EXP2(S_TANH * c1##S) + 1.0f));        \
        HOUT = h1##S;                                                         \
    } while (0)

// ---------------- kernel 1: fused 2-layer LSTM, 2 chains per thread -------
// 4 lanes per batch element; each thread runs TWO independent batch elements
// (b and b+16384) of the SAME rnn: same weights, doubled ILP. The second
// chain's ops fill the first chain's DPP/trans hazard+latency slots (R6-R10:
// four codings all stuck at ~480 busy-cyc/step -> dependency-floor bound,
// not issue bound). 512 blocks -> 2 waves/SIMD; waves_per_eu(2,2) frees the
// full 256-reg budget.
__global__ __launch_bounds__(256)
__attribute__((amdgpu_waves_per_eu(2, 2))) void k_lstm(
    const float* __restrict__ x, LW w, const float* __restrict__ u,
    __hip_bfloat16* __restrict__ hh, float* __restrict__ otherp)
{
    int gid = blockIdx.x * 256 + threadIdx.x;   // 131072 threads
    int q = gid & 3;
    int pidx = gid >> 2;                 // element-pair id in [0, 32768)
    int r = pidx >> 14;                  // wave-uniform (16384 pairs per r)
    int bb = pidx & 16383;               // chain A: b=bb ; chain B: b=bb+16384

    const float* Wih0 = w.p[r * 8 + 0];
    const float* Whh0 = w.p[r * 8 + 1];
    const float* bih0 = w.p[r * 8 + 2];
    const float* bhh0 = w.p[r * 8 + 3];
    const float* Wih1 = w.p[r * 8 + 4];
    const float* Whh1 = w.p[r * 8 + 5];
    const float* bih1 = w.p[r * 8 + 6];
    const float* bhh1 = w.p[r * 8 + 7];

    float wx0[4], bb0[4], bb1[4];
    h16x2 w0a[4], w0b[4];
    h16x2 w1h[4][4];
#pragma unroll
    for (int G = 0; G < 4; ++G) {
        int j = 4 * G + q;
        float sc = (G == 2) ? S_TANH : S_SIG;
        wx0[G] = Wih0[j] * sc;
        bb0[G] = (bih0[j] + bhh0[j]) * sc;
        bb1[G] = (bih1[j] + bhh1[j]) * sc;
        w0a[G] = pkh(Whh0[j * 4 + 0] * sc, Whh0[j * 4 + 1] * sc);
        w0b[G] = pkh(Whh0[j * 4 + 2] * sc, Whh0[j * 4 + 3] * sc);
#pragma unroll
        for (int k = 0; k < 4; ++k)
            w1h[G][k] = pkh(Wih1[j * 4 + k] * sc, Whh1[j * 4 + k] * sc);
    }

    const float* xpA = x + ((size_t)bb * 2 + r) * TSEQ;
    const float* xpB = x + ((size_t)(bb + 16384) * 2 + r) * TSEQ;
    const float* up = u + r * TSEQ;
    __hip_bfloat16* hpA = hh + ((size_t)r * BATCH + bb) * 800 + q * 4;
    __hip_bfloat16* hpB = hpA + (size_t)16384 * 800;

    float h0A = 0.f, c0A = 0.f, h1A = 0.f, c1A = 0.f;
    float h0B = 0.f, c0B = 0.f, h1B = 0.f, c1B = 0.f;
    float accA = 0.f, accB = 0.f;

    float4 xvA = *(const float4*)xpA;
    float4 xvB = *(const float4*)xpB;
    float4 uv = *(const float4*)up;

    for (int tb = 0; tb < TSEQ; tb += 4) {
        float xA0 = xvA.x, xA1 = xvA.y, xA2 = xvA.z, xA3 = xvA.w;
        float xB0 = xvB.x, xB1 = xvB.y, xB2 = xvB.z, xB3 = xvB.w;
        float u0 = uv.x, u1 = uv.y, u2 = uv.z, u3 = uv.w;
        if (tb + 4 < TSEQ) {
            xvA = *(const float4*)(xpA + tb + 4);
            xvB = *(const float4*)(xpB + tb + 4);
            uv  = *(const float4*)(up + tb + 4);
        }
        accA = fmaf(xA0, u0, accA); accB = fmaf(xB0, u0, accB);
        accA = fmaf(xA1, u1, accA); accB = fmaf(xB1, u1, accB);
        accA = fmaf(xA2, u2, accA); accB = fmaf(xB2, u2, accB);
        accA = fmaf(xA3, u3, accA); accB = fmaf(xB3, u3, accB);

        float oA0, oA1, oA2, oA3, oB0, oB1, oB2, oB3;
        LSTM_STEP(A, xA0, oA0); LSTM_STEP(B, xB0, oB0);
        LSTM_STEP(A, xA1, oA1); LSTM_STEP(B, xB1, oB1);
        LSTM_STEP(A, xA2, oA2); LSTM_STEP(B, xB2, oB2);
        LSTM_STEP(A, xA3, oA3); LSTM_STEP(B, xB3, oB3);

        ushort4 pkA, pkB;
        pkA.x = (unsigned short)f2bfs(oA0);
        pkA.y = (unsigned short)f2bfs(oA1);
        pkA.z = (unsigned short)f2bfs(oA2);
        pkA.w = (unsigned short)f2bfs(oA3);
        pkB.x = (unsigned short)f2bfs(oB0);
        pkB.y = (unsigned short)f2bfs(oB1);
        pkB.z = (unsigned short)f2bfs(oB2);
        pkB.w = (unsigned short)f2bfs(oB3);
        *(ushort4*)(hpA + tb * 4) = pkA;
        *(ushort4*)(hpB + tb * 4) = pkB;
    }
    if (q == 0) {
        otherp[(size_t)r * BATCH + bb] = accA;
        otherp[(size_t)r * BATCH + bb + 16384] = accB;
    }
}

// ---------------- kernel 2: pipelined bf16 GEMM  z = tanh(hh @ W.T + b) ----------------
__global__ __launch_bounds__(256) void k_gemm(
    const __hip_bfloat16* __restrict__ hh,
    const __hip_bfloat16* __restrict__ WHbf, const __hip_bfloat16* __restrict__ WLbf,
    const float* __restrict__ bH, const float* __restrict__ bL,
    __hip_bfloat16* __restrict__ zws)
{
    __shared__ __hip_bfloat16 As[2][128 * 32];
    __shared__ __hip_bfloat16 Bs[2][128 * 32];
    int tid = threadIdx.x;
    int f = blockIdx.y;
    int m0 = blockIdx.x * 128;
    const __hip_bfloat16* A = hh + (size_t)f * BATCH * 800 + (size_t)m0 * 800;
    const __hip_bfloat16* Wb = f ? WLbf : WHbf;
    const float* bias = f ? bL : bH;

    int wv = tid >> 6, lane = tid & 63, l15 = lane & 15, quad = lane >> 4;
    const __hip_bfloat16* ga = A + (size_t)(tid >> 2) * 800 + (tid & 3) * 8;
    const __hip_bfloat16* gb = Wb + (size_t)(tid >> 2) * 800 + (tid & 3) * 8;

    floatx4 acc[2][8] = {};

#define PREFETCH(kc, buf)                                              \
    do {                                                               \
        __hip_bfloat16* la = &As[buf][wv * 512];                       \
        __hip_bfloat16* lb = &Bs[buf][wv * 512];                       \
        async16(la,        ga + (kc) * 32);                            \
        async16(lb,        gb + (kc) * 32);                            \
        async16(la + 2048, ga + 64 * 800 + (kc) * 32);                 \
        async16(lb + 2048, gb + 64 * 800 + (kc) * 32);                 \
    } while (0)

    PREFETCH(0, 0);
    for (int kc = 0; kc < 25; ++kc) {
        __syncthreads();
        if (kc < 24) PREFETCH(kc + 1, (kc + 1) & 1);
        int buf = kc & 1;
        short8 af0 = *(const short8*)(const void*)&As[buf][(wv * 32 + l15) * 32 + quad * 8];
        short8 af1 = *(const short8*)(const void*)&As[buf][(wv * 32 + 16 + l15) * 32 + quad * 8];
#pragma unroll
        for (int nt = 0; nt < 8; ++nt) {
            short8 bfr = *(const short8*)(const void*)&Bs[buf][(nt * 16 + l15) * 32 + quad * 8];
            acc[0][nt] = __builtin_amdgcn_mfma_f32_16x16x32_bf16(af0, bfr, acc[0][nt], 0, 0, 0);
            acc[1][nt] = __builtin_amdgcn_mfma_f32_16x16x32_bf16(af1, bfr, acc[1][nt], 0, 0, 0);
        }
    }
#undef PREFETCH

    float bv[8];
#pragma unroll
    for (int nt = 0; nt < 8; ++nt) bv[nt] = bias[nt * 16 + l15];
#pragma unroll
    for (int mt = 0; mt < 2; ++mt)
#pragma unroll
        for (int nt = 0; nt < 8; ++nt)
#pragma unroll
            for (int rg = 0; rg < 4; ++rg) {
                int row = m0 + wv * 32 + mt * 16 + quad * 4 + rg;
                int col = f * 128 + nt * 16 + l15;
                zws[(size_t)row * 256 + col] =
                    __float2bfloat16(fast_tanh(acc[mt][nt][rg] + bv[nt]));
            }
}

// ---------------- kernel 3: MLP tail on z ----------------
__global__ __launch_bounds__(256) void k_tail(
    const __hip_bfloat16* __restrict__ zws,
    const __hip_bfloat16* __restrict__ W1bf, const __hip_bfloat16* __restrict__ W2bf,
    const float* __restrict__ b1, const float* __restrict__ b2,
    const float* __restrict__ W3, const float* __restrict__ u,
    const float* __restrict__ otherp, float* __restrict__ out)
{
    __shared__ short z1sh[64 * 104];
    __shared__ float z2sh[64 * 49];
    int tid = threadIdx.x;
    int wv = tid >> 6, lane = tid & 63, l15 = lane & 15, quad = lane >> 4;
    int m0 = blockIdx.x * 64;

    for (int i = tid; i < 64 * 24; i += 256) {
        int rr = i / 24, cc = 80 + (i - rr * 24);
        z1sh[rr * 104 + cc] = 0;
    }

    // z1 = tanh(z @ W1.T + b1)   M=64 K=256 N=80
    {
        floatx4 acc[5] = {};
#pragma unroll
        for (int kc = 0; kc < 8; ++kc) {
            short8 af = *(const short8*)(const void*)
                (zws + (size_t)(m0 + wv * 16 + l15) * 256 + kc * 32 + quad * 8);
#pragma unroll
            for (int nt = 0; nt < 5; ++nt) {
                short8 bfr = *(const short8*)(const void*)
                    (W1bf + (size_t)(nt * 16 + l15) * 256 + kc * 32 + quad * 8);
                acc[nt] = __builtin_amdgcn_mfma_f32_16x16x32_bf16(af, bfr, acc[nt], 0, 0, 0);
            }
        }
#pragma unroll
        for (int nt = 0; nt < 5; ++nt) {
            int n = nt * 16 + l15;
            float bb = b1[n];
#pragma unroll
            for (int rg = 0; rg < 4; ++rg) {
                int ml = wv * 16 + quad * 4 + rg;
                z1sh[ml * 104 + n] = f2bfs(fast_tanh(acc[nt][rg] + bb));
            }
        }
    }
    __syncthreads();

    // z2 = tanh(z1 @ W2.T + b2)  M=64 K=96(pad) N=48(keep 40)
    {
        floatx4 acc[3] = {};
#pragma unroll
        for (int kc = 0; kc < 3; ++kc) {
            short8 af = *(const short8*)(const void*)
                &z1sh[(wv * 16 + l15) * 104 + kc * 32 + quad * 8];
#pragma unroll
            for (int nt = 0; nt < 3; ++nt) {
                short8 bfr = *(const short8*)(const void*)
                    (W2bf + (size_t)(nt * 16 + l15) * 96 + kc * 32 + quad * 8);
                acc[nt] = __builtin_amdgcn_mfma_f32_16x16x32_bf16(af, bfr, acc[nt], 0, 0, 0);
            }
        }
#pragma unroll
        for (int nt = 0; nt < 3; ++nt) {
            int n = nt * 16 + l15;
            if (n < 40) {
                float bb = b2[n];
#pragma unroll
                for (int rg = 0; rg < 4; ++rg) {
                    int ml = wv * 16 + quad * 4 + rg;
                    z2sh[ml * 49 + n] = fast_tanh(acc[nt][rg] + bb);
                }
            }
        }
    }
    __syncthreads();

    if (tid < 64) {
        int grow = m0 + tid;
        float s = u[400] + otherp[grow] + otherp[BATCH + grow];
        for (int j = 0; j < 40; ++j) s = fmaf(z2sh[tid * 49 + j], W3[j], s);
        out[grow] = fast_sigmoid(s);
    }
}

extern "C" void kernel_launch(void* const* d_in, const int* in_sizes, int n_in,
                              void* d_out, int out_size, void* d_ws, size_t ws_size,
                              hipStream_t stream)
{
    const float* x = (const float*)d_in[0];
    LW w;
    for (int i = 0; i < 16; ++i) w.p[i] = (const float*)d_in[1 + i];
    const float* Wp = (const float*)d_in[17];
    const float* bp = (const float*)d_in[18];
    const float* WH = (const float*)d_in[19];
    const float* bH = (const float*)d_in[20];
    const float* WL = (const float*)d_in[21];
    const float* bL = (const float*)d_in[22];
    const float* W1 = (const float*)d_in[23];
    const float* b1 = (const float*)d_in[24];
    const float* W2 = (const float*)d_in[25];
    const float* b2 = (const float*)d_in[26];
    const float* W3 = (const float*)d_in[27];
    const float* b3 = (const float*)d_in[28];

    char* ws = (char*)d_ws;
    __hip_bfloat16* hh   = (__hip_bfloat16*)(ws + WS_HH);
    __hip_bfloat16* WHbf = (__hip_bfloat16*)(ws + WS_WHB);
    __hip_bfloat16* WLbf = (__hip_bfloat16*)(ws + WS_WLB);
    __hip_bfloat16* W1bf = (__hip_bfloat16*)(ws + WS_W1B);
    __hip_bfloat16* W2bf = (__hip_bfloat16*)(ws + WS_W2B);
    float* u      = (float*)(ws + WS_U);
    float* otherp = (float*)(ws + WS_OT);
    __hip_bfloat16* zws = (__hip_bfloat16*)(ws + WS_Z);
    float* out = (float*)d_out;

    k_prep<<<400, 256, 0, stream>>>(WH, WL, W1, W2, W3, Wp, bp, b3,
                                    WHbf, WLbf, W1bf, W2bf, u);
    k_lstm<<<512, 256, 0, stream>>>(x, w, u, hh, otherp);
    k_gemm<<<dim3(256, 2), 256, 0, stream>>>(hh, WHbf, WLbf, bH, bL, zws);
    k_tail<<<512, 256, 0, stream>>>(zws, W1bf, W2bf, b1, b2, W3, u, otherp, out);
}